// Round 8
// baseline (1469.194 us; speedup 1.0000x reference)
//
#include <hip/hip_runtime.h>

// Problem shapes (fixed by setup_inputs)
constexpr int NB = 32;       // batch
constexpr int NL = 8400;     // anchors
constexpr int NC = 1;        // classes
constexpr int NG = 50;       // max gts
constexpr int NKP = 17;      // keypoints
constexpr int TOPK = 13;
constexpr int BLTOT = NB * NL;
constexpr int NROW = NB * NG;           // 1600
constexpr int CAP = 1024;               // candidate capacity per row
constexpr int JBLK = (NL + 255) / 256;  // 33 anchor-blocks per batch
constexpr int GRID = 2048;              // 8 blocks/CU x 256 CUs: co-resident BY CONSTRUCTION
                                        // (VGPR=32<=64, LDS=1KB -> 8 blocks/CU resource-legal)
constexpr int GSTRIDE = GRID * 256;     // 524288 threads
constexpr float FEPS = 1e-9f;

typedef float f32x4 __attribute__((ext_vector_type(4)));  // native vec for nontemporal

__device__ __forceinline__ float iou_gp(const float4 g, const float4 p, float garea) {
    const float ix1 = fmaxf(g.x, p.x), iy1 = fmaxf(g.y, p.y);
    const float ix2 = fminf(g.z, p.z), iy2 = fminf(g.w, p.w);
    const float iw = fmaxf(ix2 - ix1, 0.f), ih = fmaxf(iy2 - iy1, 0.f);
    const float inter = iw * ih;
    const float parea = (p.z - p.x) * (p.w - p.y);
    return inter / (garea + parea - inter + FEPS);
}

// Software grid barrier: monotone counter, device-scope atomics.
// Safe because all GRID blocks are co-resident (launch_bounds(256,8) => 8 blocks/CU).
__device__ __forceinline__ void grid_barrier(unsigned* __restrict__ cnt, unsigned target) {
    __syncthreads();
    if (threadIdx.x == 0) {
        __threadfence();                 // release prior writes device-wide
        atomicAdd(cnt, 1u);              // device scope by default (G12)
        while (__hip_atomic_load(cnt, __ATOMIC_ACQUIRE, __HIP_MEMORY_SCOPE_AGENT) < target)
            __builtin_amdgcn_s_sleep(8);
        __threadfence();                 // acquire fence for non-atomic data
    }
    __syncthreads();
}

// One plain kernel, 4 phases separated by software grid barriers:
//  A: per-anchor claims-zero + candidate lists (in-box anchors per active gt)
//  B: per-(b,gt) wave top-13 -> claim bitmask (exact JAX tie-break)
//  C: per-anchor resolve (mps>1 -> is_max_iou argmax) + row maxima atomics
//  D: outputs (labels/bboxes/scores/agi_flat + nontemporal pose stream)
__global__ __launch_bounds__(256, 8) void fused_kernel(
    const float* __restrict__ pred_scores, const float* __restrict__ pred_bboxes,
    const float* __restrict__ anchor_points, const int* __restrict__ gt_labels,
    const float* __restrict__ gt_bboxes, const float* __restrict__ gt_poses,
    const float* __restrict__ pad_gt_mask, const int* __restrict__ bg_ptr,
    unsigned* __restrict__ barcnt,
    unsigned long long* __restrict__ claims, int* __restrict__ cand_cnt,
    int* __restrict__ cand, int* __restrict__ agi_arr, float* __restrict__ align_arr,
    unsigned* __restrict__ rma, unsigned* __restrict__ rmi,
    float* __restrict__ out)
{
    const int tid = threadIdx.x;
    const int bid = blockIdx.x;
    const int gid = bid * 256 + tid;

    // ---------------- Phase A: candidates + claims-zero ----------------
    {
        __shared__ float4 gbox[NG];
        __shared__ int gact[NG];
        for (int tile = bid; tile < NB * JBLK; tile += GRID) {
            const int b = tile / JBLK;
            const int jb = (tile % JBLK) * 256;
            __syncthreads();             // protect LDS reuse across tiles
            if (tid < NG) {
                gbox[tid] = reinterpret_cast<const float4*>(gt_bboxes)[b * NG + tid];
                gact[tid] = pad_gt_mask[b * NG + tid] > 0.f;
            }
            __syncthreads();
            const int j = jb + tid;
            if (j < NL) {
                claims[b * NL + j] = 0ull;
                const float2 a = reinterpret_cast<const float2*>(anchor_points)[j];
                for (int i = 0; i < NG; ++i) {
                    const float4 g = gbox[i];
                    const float din = fminf(fminf(a.x - g.x, a.y - g.y),
                                            fminf(g.z - a.x, g.w - a.y));
                    if (din > FEPS && gact[i]) {
                        const int row = b * NG + i;
                        const int slot = atomicAdd(&cand_cnt[row], 1);
                        if (slot < CAP) cand[row * CAP + slot] = j;
                    }
                }
            }
        }
    }
    grid_barrier(barcnt, GRID);

    // ---------------- Phase B: wave-per-row top-13 ----------------
    {
        const int row = bid * 4 + (tid >> 6);     // 2048*4 = 8192 >= 1600: single pass
        const int lane = tid & 63;
        if (row < NROW && pad_gt_mask[row] > 0.f) {
            const int b = row / NG, i = row % NG;
            const float4 g = reinterpret_cast<const float4*>(gt_bboxes)[row];
            const float garea = (g.z - g.x) * (g.w - g.y);
            const int lab = gt_labels[row];
            const int cnt = min(cand_cnt[row], CAP);

            float v[16]; int jj[16];
            #pragma unroll
            for (int s = 0; s < 16; ++s) {
                float mv = -1.f; int mj = NL + lane;   // sentinel, never claimed
                const int c = s * 64 + lane;
                if (c < cnt) {
                    const int j = cand[row * CAP + c];
                    const float4 p = reinterpret_cast<const float4*>(pred_bboxes)[b * NL + j];
                    const float iou = iou_gp(g, p, garea);
                    const float sc = pred_scores[(b * NL + j) * NC + lab];
                    const float i2 = iou * iou;
                    mv = sc * i2 * i2 * i2;
                    mj = j;
                }
                v[s] = mv; jj[s] = mj;
            }

            int ct = 0;
            for (int t = 0; t < TOPK; ++t) {
                float bv = -1.f; int bj = 0x7fffffff;
                #pragma unroll
                for (int s = 0; s < 16; ++s)
                    if (v[s] > bv || (v[s] == bv && jj[s] < bj)) { bv = v[s]; bj = jj[s]; }
                for (int off = 32; off; off >>= 1) {
                    const float v2 = __shfl_xor(bv, off);
                    const int   j2 = __shfl_xor(bj, off);
                    if (v2 > bv || (v2 == bv && j2 < bj)) { bv = v2; bj = j2; }
                }
                if (bv <= 0.f) break;          // remaining slots are zero-fill
                if (lane == 0) atomicOr(&claims[b * NL + bj], 1ull << i);
                ++ct;
                #pragma unroll
                for (int s = 0; s < 16; ++s) if (jj[s] == bj) v[s] = -1.f;
            }

            const int needed = TOPK - ct;      // zero-fill: smallest-index zero-metric anchors
            if (needed > 0) {
                int zcum = 0;
                for (int base = 0; base < NL && zcum < needed; base += 64) {
                    const int j = base + lane;
                    bool zero = false, ing = false;
                    if (j < NL) {
                        const float2 a = reinterpret_cast<const float2*>(anchor_points)[j];
                        const float din = fminf(fminf(a.x - g.x, a.y - g.y),
                                                fminf(g.z - a.x, g.w - a.y));
                        ing = din > FEPS;      // only bit i of the in-gts mask is needed
                        if (!ing) {
                            zero = true;
                        } else {
                            const float4 p = reinterpret_cast<const float4*>(pred_bboxes)[b * NL + j];
                            const float iou = iou_gp(g, p, garea);
                            const float sc = pred_scores[(b * NL + j) * NC + lab];
                            const float i2 = iou * iou;
                            zero = (sc * i2 * i2 * i2 == 0.f);
                        }
                    }
                    const unsigned long long bal = __ballot(zero);
                    const int rank = zcum + __popcll(bal & ((1ull << lane) - 1ull));
                    if (zero && ing && rank < needed)
                        atomicOr(&claims[b * NL + j], 1ull << i);
                    zcum += __popcll(bal);
                }
            }
        }
    }
    grid_barrier(barcnt, 2 * GRID);

    // ---------------- Phase C: per-anchor resolve ----------------
    for (int idx = gid; idx < BLTOT; idx += GSTRIDE) {
        const int b = idx / NL;
        const unsigned long long M = claims[idx];
        const int mps = __popcll(M);
        int agi = -1;
        float av = 0.f;
        if (mps >= 1) {
            const float4 p = reinterpret_cast<const float4*>(pred_bboxes)[idx];
            if (mps == 1) {
                agi = __builtin_ctzll(M);
            } else {
                // reference: column replaced by is_max_iou over ALL gts (incl. padded),
                // jnp.argmax first-occurrence tie-break -> strict '>'
                float best = -1.f;
                for (int i = 0; i < NG; ++i) {
                    const float4 g = reinterpret_cast<const float4*>(gt_bboxes)[b * NG + i];
                    const float ga = (g.z - g.x) * (g.w - g.y);
                    const float iou = iou_gp(g, p, ga);
                    if (iou > best) { best = iou; agi = i; }
                }
            }
            const float4 g = reinterpret_cast<const float4*>(gt_bboxes)[b * NG + agi];
            const float ga = (g.z - g.x) * (g.w - g.y);
            const float iou = iou_gp(g, p, ga);
            const int lab = gt_labels[b * NG + agi];
            const float s = pred_scores[idx * NC + lab];
            const float i2 = iou * iou;
            av = s * i2 * i2 * i2;
            atomicMax(&rma[b * NG + agi], __float_as_uint(av));
            atomicMax(&rmi[b * NG + agi], __float_as_uint(iou));
        }
        agi_arr[idx] = agi;
        align_arr[idx] = av;
    }
    grid_barrier(barcnt, 3 * GRID);

    // ---------------- Phase D: outputs ----------------
    float* labels = out;
    float* bboxes = out + (size_t)BLTOT;
    float* poses  = out + (size_t)5 * BLTOT;
    float* scores = out + (size_t)56 * BLTOT;
    float* agif   = out + (size_t)57 * BLTOT;
    const int bg = *bg_ptr;

    for (int idx = gid; idx < BLTOT; idx += GSTRIDE) {
        const int b = idx / NL;
        const int agi = agi_arr[idx];
        const int ag = (agi < 0) ? 0 : agi;    // reference gathers gt 0 when unassigned
        const int lab = gt_labels[b * NG + ag];

        labels[idx] = (agi >= 0) ? (float)lab : (float)bg;
        reinterpret_cast<float4*>(bboxes)[idx] =
            reinterpret_cast<const float4*>(gt_bboxes)[b * NG + ag];
        agif[idx] = (float)(ag + b * NG);

        float sc = 0.f;
        if (agi >= 0 && lab != bg) {           // one_hot with bg column removed
            const float mm = __uint_as_float(rma[b * NG + agi]);
            const float mi = __uint_as_float(rmi[b * NG + agi]);
            sc = align_arr[idx] / (mm + FEPS) * mi;
        }
        scores[idx] = sc;
    }

    // poses gather: grid-stride over float4 quads, coalesced nontemporal writes
    constexpr int NQ = BLTOT * (NKP * 3) / 4;  // 3,427,200
    constexpr int RL = NKP * 3;                // 51
    for (int q = gid; q < NQ; q += GSTRIDE) {
        const int e0 = q * 4;
        const int p = e0 / RL;                 // magic-mul const div
        const int r0 = e0 - p * RL;
        int a0 = agi_arr[p]; if (a0 < 0) a0 = 0;
        const float* src = &gt_poses[((p / NL) * NG + a0) * RL];
        f32x4 o;
        #pragma unroll
        for (int c = 0; c < 4; ++c) {
            const int r = r0 + c;
            if (r < RL) {
                o[c] = src[r];
            } else {                           // quad crosses into next anchor (<=1 crossing)
                const int p1 = p + 1;
                int a1 = agi_arr[p1]; if (a1 < 0) a1 = 0;
                o[c] = gt_poses[((p1 / NL) * NG + a1) * RL + (r - RL)];
            }
        }
        __builtin_nontemporal_store(o, reinterpret_cast<f32x4*>(poses) + q);
    }
}

extern "C" void kernel_launch(void* const* d_in, const int* in_sizes, int n_in,
                              void* d_out, int out_size, void* d_ws, size_t ws_size,
                              hipStream_t stream)
{
    const float* pred_scores   = (const float*)d_in[0];
    const float* pred_bboxes   = (const float*)d_in[1];
    // d_in[2] pred_poses: unused by the reference
    const float* anchor_points = (const float*)d_in[3];
    const int*   gt_labels     = (const int*)d_in[4];
    const float* gt_bboxes     = (const float*)d_in[5];
    const float* gt_poses      = (const float*)d_in[6];
    const float* pad_gt_mask   = (const float*)d_in[7];
    const int*   bg_ptr        = (const int*)d_in[8];

    // workspace layout. Zeroed region first: [barcnt|rma|rmi|cand_cnt] (19.2 KB)
    char* w = (char*)d_ws;
    size_t off = 0;
    unsigned* barcnt = (unsigned*)(w + off); off += 256;             // padded cacheline
    unsigned* rma = (unsigned*)(w + off); off += (size_t)NROW * 4;   // 6,400
    unsigned* rmi = (unsigned*)(w + off); off += (size_t)NROW * 4;   // 6,400
    int* cand_cnt = (int*)(w + off); off += (size_t)NROW * 4;        // 6,400
    const size_t zero_bytes = off;
    unsigned long long* claims = (unsigned long long*)(w + off); off += (size_t)BLTOT * 8;
    int*   agi_arr   = (int*)(w + off); off += (size_t)BLTOT * 4;
    float* align_arr = (float*)(w + off); off += (size_t)BLTOT * 4;
    int* cand = (int*)(w + off); off += (size_t)NROW * CAP * 4;

    (void)hipMemsetAsync(d_ws, 0, zero_bytes, stream);  // claims zeroed in phase A

    fused_kernel<<<GRID, 256, 0, stream>>>(
        pred_scores, pred_bboxes, anchor_points, gt_labels, gt_bboxes, gt_poses,
        pad_gt_mask, bg_ptr, barcnt, claims, cand_cnt, cand, agi_arr, align_arr,
        rma, rmi, (float*)d_out);
}

// Round 10
// 1190.300 us; speedup vs baseline: 1.2343x; 1.2343x over previous
//
#include <hip/hip_runtime.h>

// Problem shapes (fixed by setup_inputs)
constexpr int NB = 32;       // batch
constexpr int NL = 8400;     // anchors
constexpr int NC = 1;        // classes
constexpr int NG = 50;       // max gts
constexpr int NKP = 17;      // keypoints
constexpr int TOPK = 13;
constexpr int BLTOT = NB * NL;
constexpr int NROW = NB * NG;           // 1600
constexpr int CAP = 1024;               // candidate capacity per row
constexpr int JBLK = (NL + 255) / 256;  // 33 anchor-blocks per batch
constexpr int GRID = 2048;              // 8 blocks/CU x 256 CUs: co-resident (VGPR=32, LDS=1KB)
constexpr int GSTRIDE = GRID * 256;     // 524288 threads
constexpr int NGRP = GRID / 64;         // 32 arrival groups of 64 blocks
constexpr float FEPS = 1e-9f;

typedef float f32x4 __attribute__((ext_vector_type(4)));  // native vec for nontemporal

__device__ __forceinline__ float iou_gp(const float4 g, const float4 p, float garea) {
    const float ix1 = fmaxf(g.x, p.x), iy1 = fmaxf(g.y, p.y);
    const float ix2 = fminf(g.z, p.z), iy2 = fminf(g.w, p.w);
    const float iw = fmaxf(ix2 - ix1, 0.f), ih = fmaxf(iy2 - iy1, 0.f);
    const float inter = iw * ih;
    const float parea = (p.z - p.x) * (p.w - p.y);
    return inter / (garea + parea - inter + FEPS);
}

// Low-contention grid barrier (all GRID blocks co-resident by construction).
// Arrive: hierarchical monotone counters (32 groups x 64 blocks, 128B-padded
// lines) -> 32 adds on one global line -> final arriver stores epoch flag.
// Wait: read-only spin on the flag line (no RMW-line stealing — the round-8
// 1.4 ms pathology was spinners hammering the SAME line arrivals must RMW).
__device__ __forceinline__ void grid_barrier(unsigned* __restrict__ grp,
                                             unsigned* __restrict__ glob,
                                             unsigned* __restrict__ go,
                                             unsigned epoch) {
    __syncthreads();
    if (threadIdx.x == 0) {
        __threadfence();                                   // release this block's writes
        const int g = blockIdx.x >> 6;
        const unsigned gv = atomicAdd(&grp[g * 32], 1u);   // 128B apart
        if (gv + 1 == epoch * 64u) {                       // last of group this epoch
            __threadfence();
            const unsigned ov = atomicAdd(glob, 1u);
            if (ov + 1 == epoch * (unsigned)NGRP) {        // last group overall
                __threadfence();
                __hip_atomic_store(go, epoch, __ATOMIC_RELEASE, __HIP_MEMORY_SCOPE_AGENT);
            }
        }
        while (__hip_atomic_load(go, __ATOMIC_ACQUIRE, __HIP_MEMORY_SCOPE_AGENT) < epoch)
            __builtin_amdgcn_s_sleep(16);
        __threadfence();                                   // acquire for non-atomic data
    }
    __syncthreads();
}

// One plain kernel, 4 phases separated by software grid barriers:
//  A: per-anchor claims-zero + candidate lists (in-box anchors per active gt)
//  B: per-(b,gt) wave top-13 -> claim bitmask (exact JAX tie-break)
//  C: per-anchor resolve (mps>1 -> is_max_iou argmax) + row maxima atomics
//  D: outputs (labels/bboxes/scores/agi_flat + nontemporal pose stream)
__global__ __launch_bounds__(256, 8) void fused_kernel(
    const float* __restrict__ pred_scores, const float* __restrict__ pred_bboxes,
    const float* __restrict__ anchor_points, const int* __restrict__ gt_labels,
    const float* __restrict__ gt_bboxes, const float* __restrict__ gt_poses,
    const float* __restrict__ pad_gt_mask, const int* __restrict__ bg_ptr,
    unsigned* __restrict__ bar_grp, unsigned* __restrict__ bar_glob,
    unsigned* __restrict__ bar_go,
    unsigned long long* __restrict__ claims, int* __restrict__ cand_cnt,
    int* __restrict__ cand, int* __restrict__ agi_arr, float* __restrict__ align_arr,
    unsigned* __restrict__ rma, unsigned* __restrict__ rmi,
    float* __restrict__ out)
{
    const int tid = threadIdx.x;
    const int bid = blockIdx.x;
    const int gid = bid * 256 + tid;

    // ---------------- Phase A: candidates + claims-zero ----------------
    {
        __shared__ float4 gbox[NG];
        __shared__ int gact[NG];
        for (int tile = bid; tile < NB * JBLK; tile += GRID) {
            const int b = tile / JBLK;
            const int jb = (tile % JBLK) * 256;
            __syncthreads();             // protect LDS reuse across tiles
            if (tid < NG) {
                gbox[tid] = reinterpret_cast<const float4*>(gt_bboxes)[b * NG + tid];
                gact[tid] = pad_gt_mask[b * NG + tid] > 0.f;
            }
            __syncthreads();
            const int j = jb + tid;
            if (j < NL) {
                claims[b * NL + j] = 0ull;
                const float2 a = reinterpret_cast<const float2*>(anchor_points)[j];
                for (int i = 0; i < NG; ++i) {
                    const float4 g = gbox[i];
                    const float din = fminf(fminf(a.x - g.x, a.y - g.y),
                                            fminf(g.z - a.x, g.w - a.y));
                    if (din > FEPS && gact[i]) {
                        const int row = b * NG + i;
                        const int slot = atomicAdd(&cand_cnt[row], 1);
                        if (slot < CAP) cand[row * CAP + slot] = j;
                    }
                }
            }
        }
    }
    grid_barrier(bar_grp, bar_glob, bar_go, 1);

    // ---------------- Phase B: wave-per-row top-13 ----------------
    {
        const int row = bid * 4 + (tid >> 6);     // 2048*4 = 8192 >= 1600: single pass
        const int lane = tid & 63;
        if (row < NROW && pad_gt_mask[row] > 0.f) {
            const int b = row / NG, i = row % NG;
            const float4 g = reinterpret_cast<const float4*>(gt_bboxes)[row];
            const float garea = (g.z - g.x) * (g.w - g.y);
            const int lab = gt_labels[row];
            const int cnt = min(cand_cnt[row], CAP);

            float v[16]; int jj[16];
            #pragma unroll
            for (int s = 0; s < 16; ++s) {
                float mv = -1.f; int mj = NL + lane;   // sentinel, never claimed
                const int c = s * 64 + lane;
                if (c < cnt) {
                    const int j = cand[row * CAP + c];
                    const float4 p = reinterpret_cast<const float4*>(pred_bboxes)[b * NL + j];
                    const float iou = iou_gp(g, p, garea);
                    const float sc = pred_scores[(b * NL + j) * NC + lab];
                    const float i2 = iou * iou;
                    mv = sc * i2 * i2 * i2;
                    mj = j;
                }
                v[s] = mv; jj[s] = mj;
            }

            int ct = 0;
            for (int t = 0; t < TOPK; ++t) {
                float bv = -1.f; int bj = 0x7fffffff;
                #pragma unroll
                for (int s = 0; s < 16; ++s)
                    if (v[s] > bv || (v[s] == bv && jj[s] < bj)) { bv = v[s]; bj = jj[s]; }
                for (int off = 32; off; off >>= 1) {
                    const float v2 = __shfl_xor(bv, off);
                    const int   j2 = __shfl_xor(bj, off);
                    if (v2 > bv || (v2 == bv && j2 < bj)) { bv = v2; bj = j2; }
                }
                if (bv <= 0.f) break;          // remaining slots are zero-fill
                if (lane == 0) atomicOr(&claims[b * NL + bj], 1ull << i);
                ++ct;
                #pragma unroll
                for (int s = 0; s < 16; ++s) if (jj[s] == bj) v[s] = -1.f;
            }

            const int needed = TOPK - ct;      // zero-fill: smallest-index zero-metric anchors
            if (needed > 0) {
                int zcum = 0;
                for (int base = 0; base < NL && zcum < needed; base += 64) {
                    const int j = base + lane;
                    bool zero = false, ing = false;
                    if (j < NL) {
                        const float2 a = reinterpret_cast<const float2*>(anchor_points)[j];
                        const float din = fminf(fminf(a.x - g.x, a.y - g.y),
                                                fminf(g.z - a.x, g.w - a.y));
                        ing = din > FEPS;      // only bit i of the in-gts mask is needed
                        if (!ing) {
                            zero = true;
                        } else {
                            const float4 p = reinterpret_cast<const float4*>(pred_bboxes)[b * NL + j];
                            const float iou = iou_gp(g, p, garea);
                            const float sc = pred_scores[(b * NL + j) * NC + lab];
                            const float i2 = iou * iou;
                            zero = (sc * i2 * i2 * i2 == 0.f);
                        }
                    }
                    const unsigned long long bal = __ballot(zero);
                    const int rank = zcum + __popcll(bal & ((1ull << lane) - 1ull));
                    if (zero && ing && rank < needed)
                        atomicOr(&claims[b * NL + j], 1ull << i);
                    zcum += __popcll(bal);
                }
            }
        }
    }
    grid_barrier(bar_grp, bar_glob, bar_go, 2);

    // ---------------- Phase C: per-anchor resolve ----------------
    for (int idx = gid; idx < BLTOT; idx += GSTRIDE) {
        const int b = idx / NL;
        const unsigned long long M = claims[idx];
        const int mps = __popcll(M);
        int agi = -1;
        float av = 0.f;
        if (mps >= 1) {
            const float4 p = reinterpret_cast<const float4*>(pred_bboxes)[idx];
            if (mps == 1) {
                agi = __builtin_ctzll(M);
            } else {
                // reference: column replaced by is_max_iou over ALL gts (incl. padded),
                // jnp.argmax first-occurrence tie-break -> strict '>'
                float best = -1.f;
                for (int i = 0; i < NG; ++i) {
                    const float4 g = reinterpret_cast<const float4*>(gt_bboxes)[b * NG + i];
                    const float ga = (g.z - g.x) * (g.w - g.y);
                    const float iou = iou_gp(g, p, ga);
                    if (iou > best) { best = iou; agi = i; }
                }
            }
            const float4 g = reinterpret_cast<const float4*>(gt_bboxes)[b * NG + agi];
            const float ga = (g.z - g.x) * (g.w - g.y);
            const float iou = iou_gp(g, p, ga);
            const int lab = gt_labels[b * NG + agi];
            const float s = pred_scores[idx * NC + lab];
            const float i2 = iou * iou;
            av = s * i2 * i2 * i2;
            atomicMax(&rma[b * NG + agi], __float_as_uint(av));
            atomicMax(&rmi[b * NG + agi], __float_as_uint(iou));
        }
        agi_arr[idx] = agi;
        align_arr[idx] = av;
    }
    grid_barrier(bar_grp, bar_glob, bar_go, 3);

    // ---------------- Phase D: outputs ----------------
    float* labels = out;
    float* bboxes = out + (size_t)BLTOT;
    float* poses  = out + (size_t)5 * BLTOT;
    float* scores = out + (size_t)56 * BLTOT;
    float* agif   = out + (size_t)57 * BLTOT;
    const int bg = *bg_ptr;

    for (int idx = gid; idx < BLTOT; idx += GSTRIDE) {
        const int b = idx / NL;
        const int agi = agi_arr[idx];
        const int ag = (agi < 0) ? 0 : agi;    // reference gathers gt 0 when unassigned
        const int lab = gt_labels[b * NG + ag];

        labels[idx] = (agi >= 0) ? (float)lab : (float)bg;
        reinterpret_cast<float4*>(bboxes)[idx] =
            reinterpret_cast<const float4*>(gt_bboxes)[b * NG + ag];
        agif[idx] = (float)(ag + b * NG);

        float sc = 0.f;
        if (agi >= 0 && lab != bg) {           // one_hot with bg column removed
            const float mm = __uint_as_float(rma[b * NG + agi]);
            const float mi = __uint_as_float(rmi[b * NG + agi]);
            sc = align_arr[idx] / (mm + FEPS) * mi;
        }
        scores[idx] = sc;
    }

    // poses gather: grid-stride over float4 quads, coalesced nontemporal writes
    constexpr int NQ = BLTOT * (NKP * 3) / 4;  // 3,427,200
    constexpr int RL = NKP * 3;                // 51
    for (int q = gid; q < NQ; q += GSTRIDE) {
        const int e0 = q * 4;
        const int p = e0 / RL;                 // magic-mul const div
        const int r0 = e0 - p * RL;
        int a0 = agi_arr[p]; if (a0 < 0) a0 = 0;
        const float* src = &gt_poses[((p / NL) * NG + a0) * RL];
        f32x4 o;
        #pragma unroll
        for (int c = 0; c < 4; ++c) {
            const int r = r0 + c;
            if (r < RL) {
                o[c] = src[r];
            } else {                           // quad crosses into next anchor (<=1 crossing)
                const int p1 = p + 1;
                int a1 = agi_arr[p1]; if (a1 < 0) a1 = 0;
                o[c] = gt_poses[((p1 / NL) * NG + a1) * RL + (r - RL)];
            }
        }
        __builtin_nontemporal_store(o, reinterpret_cast<f32x4*>(poses) + q);
    }
}

extern "C" void kernel_launch(void* const* d_in, const int* in_sizes, int n_in,
                              void* d_out, int out_size, void* d_ws, size_t ws_size,
                              hipStream_t stream)
{
    const float* pred_scores   = (const float*)d_in[0];
    const float* pred_bboxes   = (const float*)d_in[1];
    // d_in[2] pred_poses: unused by the reference
    const float* anchor_points = (const float*)d_in[3];
    const int*   gt_labels     = (const int*)d_in[4];
    const float* gt_bboxes     = (const float*)d_in[5];
    const float* gt_poses      = (const float*)d_in[6];
    const float* pad_gt_mask   = (const float*)d_in[7];
    const int*   bg_ptr        = (const int*)d_in[8];

    // workspace layout. Zeroed region first: [go|glob|grp|rma|rmi|cand_cnt]
    char* w = (char*)d_ws;
    size_t off = 0;
    unsigned* bar_go   = (unsigned*)(w + off); off += 128;           // poll line
    unsigned* bar_glob = (unsigned*)(w + off); off += 128;           // global arrive line
    unsigned* bar_grp  = (unsigned*)(w + off); off += (size_t)NGRP * 128;  // 32 group lines
    unsigned* rma = (unsigned*)(w + off); off += (size_t)NROW * 4;   // 6,400
    unsigned* rmi = (unsigned*)(w + off); off += (size_t)NROW * 4;   // 6,400
    int* cand_cnt = (int*)(w + off); off += (size_t)NROW * 4;        // 6,400
    const size_t zero_bytes = off;
    unsigned long long* claims = (unsigned long long*)(w + off); off += (size_t)BLTOT * 8;
    int*   agi_arr   = (int*)(w + off); off += (size_t)BLTOT * 4;
    float* align_arr = (float*)(w + off); off += (size_t)BLTOT * 4;
    int* cand = (int*)(w + off); off += (size_t)NROW * CAP * 4;

    (void)hipMemsetAsync(d_ws, 0, zero_bytes, stream);  // claims zeroed in phase A

    fused_kernel<<<GRID, 256, 0, stream>>>(
        pred_scores, pred_bboxes, anchor_points, gt_labels, gt_bboxes, gt_poses,
        pad_gt_mask, bg_ptr, bar_grp, bar_glob, bar_go, claims, cand_cnt, cand,
        agi_arr, align_arr, rma, rmi, (float*)d_out);
}

// Round 12
// 201.383 us; speedup vs baseline: 7.2955x; 5.9106x over previous
//
#include <hip/hip_runtime.h>

// Problem shapes (fixed by setup_inputs)
constexpr int NB = 32;       // batch
constexpr int NL = 8400;     // anchors
constexpr int NC = 1;        // classes
constexpr int NG = 50;       // max gts
constexpr int NKP = 17;      // keypoints
constexpr int TOPK = 13;
constexpr int BLTOT = NB * NL;
constexpr int NROW = NB * NG;        // 1600
constexpr int CAP = 1024;            // candidate capacity per row (16 slots/lane)
constexpr float FEPS = 1e-9f;

typedef float f32x4 __attribute__((ext_vector_type(4)));  // native vec for nontemporal

__device__ __forceinline__ float iou_gp(const float4 g, const float4 p, float garea) {
    const float ix1 = fmaxf(g.x, p.x), iy1 = fmaxf(g.y, p.y);
    const float ix2 = fminf(g.z, p.z), iy2 = fminf(g.w, p.w);
    const float iw = fmaxf(ix2 - ix1, 0.f), ih = fmaxf(iy2 - iy1, 0.f);
    const float inter = iw * ih;
    const float parea = (p.z - p.x) * (p.w - p.y);
    return inter / (garea + parea - inter + FEPS);
}

// ---------------- Kernel 1: wave-per-row candidate scan + top-13 claims ----------------
// Each wave (4 per block) owns one (b,gt) row. It scans all anchors with the
// cheap in-box test (ballot-compact into an LDS candidate list, ascending j),
// evaluates the metric only for candidates, then claims top-13 with the exact
// JAX tie-break (value desc, index asc); zero-metric slots are filled with the
// smallest-index zero-metric in-box anchors. Claims require in-box.
__global__ __launch_bounds__(256) void topk_claim_kernel(
    const float* __restrict__ pred_scores, const float* __restrict__ pred_bboxes,
    const float* __restrict__ anchor_points, const int* __restrict__ gt_labels,
    const float* __restrict__ gt_bboxes, const float* __restrict__ pad_gt_mask,
    unsigned long long* __restrict__ claims)
{
    __shared__ int cl[4][CAP];               // 16 KB candidate lists
    const int w = threadIdx.x >> 6;
    const int lane = threadIdx.x & 63;
    const int row = blockIdx.x * 4 + w;      // 400 blocks x 4 = 1600 rows exact
    if (pad_gt_mask[row] <= 0.f) return;     // wave-uniform exit
    const int b = row / NG, i = row % NG;
    const float4 g = reinterpret_cast<const float4*>(gt_bboxes)[row];
    const float garea = (g.z - g.x) * (g.w - g.y);
    const int lab = gt_labels[row];

    // build candidate list (in-box anchors, ascending j)
    int cnt = 0;
    for (int base = 0; base < NL; base += 64) {
        const int j = base + lane;
        bool in = false;
        if (j < NL) {
            const float2 a = reinterpret_cast<const float2*>(anchor_points)[j];
            const float din = fminf(fminf(a.x - g.x, a.y - g.y),
                                    fminf(g.z - a.x, g.w - a.y));
            in = din > FEPS;
        }
        const unsigned long long bal = __ballot(in);
        const int rank = cnt + __popcll(bal & ((1ull << lane) - 1ull));
        if (in && rank < CAP) cl[w][rank] = j;
        cnt += __popcll(bal);
    }
    cnt = min(cnt, CAP);

    // evaluate metric for candidates (16 register slots/lane, static idx)
    float v[16]; int jj[16];
    #pragma unroll
    for (int s = 0; s < 16; ++s) {
        float mv = -1.f; int mj = NL + lane;     // sentinel (>= NL, never claimed)
        const int c = s * 64 + lane;
        if (c < cnt) {
            const int j = cl[w][c];
            const float4 p = reinterpret_cast<const float4*>(pred_bboxes)[b * NL + j];
            const float iou = iou_gp(g, p, garea);
            const float sc = pred_scores[(b * NL + j) * NC + lab];
            const float i2 = iou * iou;
            mv = sc * i2 * i2 * i2;
            mj = j;
        }
        v[s] = mv; jj[s] = mj;
    }

    int ct = 0;
    for (int t = 0; t < TOPK; ++t) {
        float bv = -1.f; int bj = 0x7fffffff;
        #pragma unroll
        for (int s = 0; s < 16; ++s)
            if (v[s] > bv || (v[s] == bv && jj[s] < bj)) { bv = v[s]; bj = jj[s]; }
        for (int off = 32; off; off >>= 1) {
            const float v2 = __shfl_xor(bv, off);
            const int   j2 = __shfl_xor(bj, off);
            if (v2 > bv || (v2 == bv && j2 < bj)) { bv = v2; bj = j2; }
        }
        if (bv <= 0.f) break;                    // remaining slots are zero-fill
        if (lane == 0) atomicOr(&claims[b * NL + bj], 1ull << i);
        ++ct;
        #pragma unroll
        for (int s = 0; s < 16; ++s) if (jj[s] == bj) v[s] = -1.f;
    }

    const int needed = TOPK - ct;   // zero-fill: smallest-index zero-metric anchors
    if (needed > 0) {
        int zcum = 0;
        for (int base = 0; base < NL && zcum < needed; base += 64) {
            const int j = base + lane;
            bool zero = false, ing = false;
            if (j < NL) {
                const float2 a = reinterpret_cast<const float2*>(anchor_points)[j];
                const float din = fminf(fminf(a.x - g.x, a.y - g.y),
                                        fminf(g.z - a.x, g.w - a.y));
                ing = din > FEPS;
                if (!ing) {
                    zero = true;
                } else {
                    const float4 p = reinterpret_cast<const float4*>(pred_bboxes)[b * NL + j];
                    const float iou = iou_gp(g, p, garea);
                    const float sc = pred_scores[(b * NL + j) * NC + lab];
                    const float i2 = iou * iou;
                    zero = (sc * i2 * i2 * i2 == 0.f);
                }
            }
            const unsigned long long bal = __ballot(zero);
            const int rank = zcum + __popcll(bal & ((1ull << lane) - 1ull));
            if (zero && ing && rank < needed)
                atomicOr(&claims[b * NL + j], 1ull << i);
            zcum += __popcll(bal);
        }
    }
}

// ---------------- Kernel 2: per-anchor resolve -> agi, align_val, row maxima ----------------
__global__ __launch_bounds__(256) void resolve_kernel(
    const float* __restrict__ pred_scores, const float* __restrict__ pred_bboxes,
    const int* __restrict__ gt_labels, const float* __restrict__ gt_bboxes,
    const unsigned long long* __restrict__ claims,
    int* __restrict__ agi_arr, float* __restrict__ align_arr,
    unsigned* __restrict__ rma, unsigned* __restrict__ rmi)
{
    const int idx = blockIdx.x * 256 + threadIdx.x;   // b*NL + j
    if (idx >= BLTOT) return;
    const int b = idx / NL;
    const unsigned long long M = claims[idx];
    const int mps = __popcll(M);
    int agi = -1;
    float av = 0.f;
    if (mps >= 1) {
        const float4 p = reinterpret_cast<const float4*>(pred_bboxes)[idx];
        if (mps == 1) {
            agi = __builtin_ctzll(M);
        } else {
            // reference: column replaced by is_max_iou over ALL gts (incl. padded),
            // jnp.argmax first-occurrence tie-break -> strict '>'
            float best = -1.f;
            for (int i = 0; i < NG; ++i) {
                const float4 g = reinterpret_cast<const float4*>(gt_bboxes)[b * NG + i];
                const float ga = (g.z - g.x) * (g.w - g.y);
                const float iou = iou_gp(g, p, ga);
                if (iou > best) { best = iou; agi = i; }
            }
        }
        const float4 g = reinterpret_cast<const float4*>(gt_bboxes)[b * NG + agi];
        const float ga = (g.z - g.x) * (g.w - g.y);
        const float iou = iou_gp(g, p, ga);
        const int lab = gt_labels[b * NG + agi];
        const float s = pred_scores[idx * NC + lab];
        const float i2 = iou * iou;
        av = s * i2 * i2 * i2;
        atomicMax(&rma[b * NG + agi], __float_as_uint(av));
        atomicMax(&rmi[b * NG + agi], __float_as_uint(iou));
    }
    agi_arr[idx] = agi;
    align_arr[idx] = av;
}

// ---------------- Kernel 3: fused labels / bboxes / scores / agi_flat / poses ----------------
__global__ __launch_bounds__(256) void final_kernel(
    const int* __restrict__ gt_labels, const float* __restrict__ gt_bboxes,
    const float* __restrict__ gt_poses,
    const int* __restrict__ agi_arr, const float* __restrict__ align_arr,
    const unsigned* __restrict__ rma, const unsigned* __restrict__ rmi,
    const int* __restrict__ bg_ptr, float* __restrict__ out)
{
    const int idx = blockIdx.x * 256 + threadIdx.x;   // exactly BLTOT threads
    const int b = idx / NL;
    const int agi = agi_arr[idx];
    const int ag = (agi < 0) ? 0 : agi;     // reference gathers gt 0 when unassigned
    const int bg = *bg_ptr;
    const int lab = gt_labels[b * NG + ag];

    float* labels = out;
    float* bboxes = out + (size_t)BLTOT;
    float* poses  = out + (size_t)5 * BLTOT;
    float* scores = out + (size_t)56 * BLTOT;
    float* agif   = out + (size_t)57 * BLTOT;

    labels[idx] = (agi >= 0) ? (float)lab : (float)bg;
    reinterpret_cast<float4*>(bboxes)[idx] =
        reinterpret_cast<const float4*>(gt_bboxes)[b * NG + ag];
    agif[idx] = (float)(ag + b * NG);

    float sc = 0.f;
    if (agi >= 0 && lab != bg) {   // one_hot with bg column removed
        const float mm = __uint_as_float(rma[b * NG + agi]);
        const float mi = __uint_as_float(rmi[b * NG + agi]);
        sc = align_arr[idx] / (mm + FEPS) * mi;
    }
    scores[idx] = sc;

    // poses gather: grid-stride over float4 quads, coalesced nontemporal writes
    constexpr int NQ = BLTOT * (NKP * 3) / 4;   // 3,427,200
    constexpr int RL = NKP * 3;                 // 51
    for (int q = idx; q < NQ; q += BLTOT) {
        const int e0 = q * 4;
        const int p = e0 / RL;                  // magic-mul const div
        const int r0 = e0 - p * RL;
        int a0 = agi_arr[p]; if (a0 < 0) a0 = 0;
        const float* src = &gt_poses[((p / NL) * NG + a0) * RL];
        f32x4 o;
        #pragma unroll
        for (int c = 0; c < 4; ++c) {
            const int r = r0 + c;
            if (r < RL) {
                o[c] = src[r];
            } else {                            // quad crosses into next anchor (<=1 crossing)
                const int p1 = p + 1;
                int a1 = agi_arr[p1]; if (a1 < 0) a1 = 0;
                o[c] = gt_poses[((p1 / NL) * NG + a1) * RL + (r - RL)];
            }
        }
        __builtin_nontemporal_store(o, reinterpret_cast<f32x4*>(poses) + q);
    }
}

extern "C" void kernel_launch(void* const* d_in, const int* in_sizes, int n_in,
                              void* d_out, int out_size, void* d_ws, size_t ws_size,
                              hipStream_t stream)
{
    const float* pred_scores   = (const float*)d_in[0];
    const float* pred_bboxes   = (const float*)d_in[1];
    // d_in[2] pred_poses: unused by the reference
    const float* anchor_points = (const float*)d_in[3];
    const int*   gt_labels     = (const int*)d_in[4];
    const float* gt_bboxes     = (const float*)d_in[5];
    const float* gt_poses      = (const float*)d_in[6];
    const float* pad_gt_mask   = (const float*)d_in[7];
    const int*   bg_ptr        = (const int*)d_in[8];

    // workspace layout. Zeroed region first: [rma|rmi|claims] (~2.17 MB, one memset)
    char* w = (char*)d_ws;
    size_t off = 0;
    unsigned* rma = (unsigned*)(w + off); off += (size_t)NROW * 4;              // 6,400
    unsigned* rmi = (unsigned*)(w + off); off += (size_t)NROW * 4;              // 6,400
    unsigned long long* claims = (unsigned long long*)(w + off); off += (size_t)BLTOT * 8;
    const size_t zero_bytes = off;
    int*   agi_arr   = (int*)  (w + off); off += (size_t)BLTOT * 4;
    float* align_arr = (float*)(w + off); off += (size_t)BLTOT * 4;

    (void)hipMemsetAsync(d_ws, 0, zero_bytes, stream);

    topk_claim_kernel<<<NROW / 4, 256, 0, stream>>>(
        pred_scores, pred_bboxes, anchor_points, gt_labels, gt_bboxes,
        pad_gt_mask, claims);

    resolve_kernel<<<(BLTOT + 255) / 256, 256, 0, stream>>>(
        pred_scores, pred_bboxes, gt_labels, gt_bboxes, claims,
        agi_arr, align_arr, rma, rmi);

    final_kernel<<<BLTOT / 256, 256, 0, stream>>>(
        gt_labels, gt_bboxes, gt_poses, agi_arr, align_arr, rma, rmi, bg_ptr,
        (float*)d_out);
}